// Round 11
// baseline (164.993 us; speedup 1.0000x reference)
//
#include <hip/hip_runtime.h>
#include <stdint.h>

typedef __attribute__((ext_vector_type(4))) int i32x4;
typedef __attribute__((ext_vector_type(16))) float f32x16;

#define MROWS 8192L
#define NCOLS 4096L
#define KDIM  4096L

#define XQ_BYTES   (MROWS * KDIM / 2)            // 16777216 (fp4, fragment-permuted)
#define WQ_BYTES   (NCOLS * KDIM / 2)            // 8388608
#define SCAL_OFF   (XQ_BYTES + WQ_BYTES)

// ---------------- reduction: sum|x| (blocks 0..511), sum|w| (blocks 512..767) ----
__global__ __launch_bounds__(256) void k_reduce_abs(const float* __restrict__ x,
                                                    const float* __restrict__ w,
                                                    float* __restrict__ partials) {
    __shared__ float sm[256];
    int b = blockIdx.x;
    int t = threadIdx.x;
    const float4* v;
    long base;
    if (b < 512) { v = (const float4*)x; base = (long)b * 16384; }
    else         { v = (const float4*)w; base = (long)(b - 512) * 16384; }
    float s = 0.f;
    for (int i = t; i < 16384; i += 256) {
        float4 q = v[base + i];
        s += fabsf(q.x) + fabsf(q.y) + fabsf(q.z) + fabsf(q.w);
    }
    sm[t] = s;
    __syncthreads();
    for (int off = 128; off > 0; off >>= 1) {
        if (t < off) sm[t] += sm[t + off];
        __syncthreads();
    }
    if (t == 0) partials[b] = sm[0];
}

// ---------------- finalize: double-precision combine, write scalars --------------
__global__ __launch_bounds__(256) void k_finalize(float* __restrict__ scal) {
    const float* partials = scal + 4;
    __shared__ double sm[256];
    int t = threadIdx.x;

    double sx = 0.0;
    for (int i = t; i < 512; i += 256) sx += (double)partials[i];
    sm[t] = sx;
    __syncthreads();
    for (int off = 128; off > 0; off >>= 1) {
        if (t < off) sm[t] += sm[t + off];
        __syncthreads();
    }
    double SX = sm[0];
    __syncthreads();

    double sw = (double)partials[512 + t];
    sm[t] = sw;
    __syncthreads();
    for (int off = 128; off > 0; off >>= 1) {
        if (t < off) sm[t] += sm[t + off];
        __syncthreads();
    }
    if (t == 0) {
        float meanx = (float)(SX / 33554432.0);
        float meanw = (float)(sm[0] / 16777216.0);
        scal[0] = 0.1f * meanx;   // delta_x
        scal[1] = 0.05f * meanw;  // delta_w
        scal[2] = meanw;          // alpha
    }
}

// ---------------- ternarize to fp4 e2m1 {-1,0,1}, fragment-permuted output -------
// Layout (X): 1KB block BX = (rowblk*32 + ktile)*2 + ks ; inside: [khalf(2)][r32(32)][16B]
__device__ __forceinline__ unsigned int nib4(float v, float delta) {
    return v > delta ? 2u : (v < -delta ? 10u : 0u);   // +1=0x2, -1=0xA, 0=0x0
}

__global__ __launch_bounds__(256) void k_quantF(const float* __restrict__ x,
                                                const float* __restrict__ w,
                                                uint4* __restrict__ xq,
                                                uint4* __restrict__ wq,
                                                const float* __restrict__ scal) {
    int wv = blockIdx.x * 4 + (threadIdx.x >> 6);   // wave task id, 0..24575
    int l = threadIdx.x & 63;

    const float* src;
    uint4* dst;
    float delta;
    int task;                        // block index within its tensor
    if (wv < 16384) {                // X: rowblk(256) x ktile(32) x ks(2)
        src = x; dst = xq; delta = scal[0]; task = wv;
    } else {                         // W: colblk(128) x ktile(32) x ks(2)
        src = w; dst = wq; delta = scal[1]; task = wv - 16384;
    }
    int rowblk = task >> 6;
    int rest = task & 63;            // ktile*2 + ks
    long row = (long)rowblk * 32 + (l & 31);
    long fidx = row * 4096 + (long)(rest >> 1) * 128 + (long)(rest & 1) * 64
              + (long)(l >> 5) * 32;
    const float4* s4 = (const float4*)(src + fidx);

    unsigned int ow[4];
#pragma unroll
    for (int c = 0; c < 4; ++c) {
        float4 q0 = s4[2 * c];
        float4 q1 = s4[2 * c + 1];
        ow[c] = nib4(q0.x, delta)
              | (nib4(q0.y, delta) << 4)
              | (nib4(q0.z, delta) << 8)
              | (nib4(q0.w, delta) << 12)
              | (nib4(q1.x, delta) << 16)
              | (nib4(q1.y, delta) << 20)
              | (nib4(q1.z, delta) << 24)
              | (nib4(q1.w, delta) << 28);
    }
    uint4 o; o.x = ow[0]; o.y = ow[1]; o.z = ow[2]; o.w = ow[3];
    dst[(long)task * 64 + l] = o;    // 64 lanes x 16B = contiguous 1KB
}

// ---- GEMM: alpha*(Xq@Wq^T), fp4 32x32x64; A via LDS ring-2, B direct-to-reg -----
#define GLOAD_LDS16(g, l)                                                             \
    __builtin_amdgcn_global_load_lds((const __attribute__((address_space(1))) void*)(g), \
                                     (__attribute__((address_space(3))) void*)(l),       \
                                     16, 0, 0)

// i32x4 -> i32x8 with undef high half (fp4 data occupies low 4 VGPRs)
#define MK8(v) __builtin_shufflevector((v), (v), 0, 1, 2, 3, -1, -1, -1, -1)

// fp4 x fp4, scales = 1.0 (E8M0 127 in every byte)
#define MFMA32(a, b, c)                                                       \
    __builtin_amdgcn_mfma_scale_f32_32x32x64_f8f6f4(MK8(a), MK8(b), (c),      \
        4, 4, 0, 0x7F7F7F7F, 0, 0x7F7F7F7F)

__global__ __launch_bounds__(512, 2) void k_gemm(const signed char* __restrict__ Xq,
                                                 const signed char* __restrict__ Wq,
                                                 float* __restrict__ out,
                                                 const float* __restrict__ scal) {
    // A-only LDS: ring of 2 slots x 16 KB; groups [wm(2)][mi(4)][ks(2)] x 1 KB
    __shared__ __attribute__((aligned(16))) signed char lds[32768];

    const float alpha = scal[2];

    // XCD-aware bijective swizzle (512 blocks, 512 % 8 == 0, cpx = 64)
    int bid = (int)blockIdx.x;
    bid = (bid & 7) * 64 + (bid >> 3);
    int bm = bid >> 4;                 // 0..31  (M/256)
    int bn = bid & 15;                 // 0..15  (N/256)
    long row0 = (long)bm * 256;
    long col0 = (long)bn * 256;

    int t = threadIdx.x;               // 0..511
    int lane = t & 63;
    int wid = t >> 6;                  // 0..7
    int wm = wid >> 2;                 // 0..1  (M half: 128 rows)
    int wn = wid & 3;                  // 0..3  (N quarter: 64 cols)

    // ---- A staging: each wave stages 2 groups (ga = wid*2 + j) ----
    // group ga = (wm*4+mi)*2+ks -> rowblk = bm*8 + (ga>>1), ks = ga&1
    const signed char* sp[2];
    int ldoff[2];
#pragma unroll
    for (int j = 0; j < 2; ++j) {
        int ga = wid * 2 + j;
        ldoff[j] = ga * 1024;
        sp[j] = Xq + (long)(bm * 8 + (ga >> 1)) * 65536 + (ga & 1) * 1024 + lane * 16;
    }

#define STAGE_A(slot, g1) do {                                                 \
    signed char* sb_ = lds + (slot) * 16384;                                   \
    GLOAD_LDS16(sp[0] + (long)(g1) * 2048, sb_ + ldoff[0]);                    \
    GLOAD_LDS16(sp[1] + (long)(g1) * 2048, sb_ + ldoff[1]);                    \
} while (0)

    // ---- B fragment pointers (direct-to-reg): (ni, ks), 1 KB contiguous ----
    const signed char* pb0 = Wq + (long)(bn * 8 + wn * 2 + 0) * 65536 + 0 * 1024 + lane * 16;
    const signed char* pb1 = Wq + (long)(bn * 8 + wn * 2 + 1) * 65536 + 0 * 1024 + lane * 16;
    const signed char* pb2 = Wq + (long)(bn * 8 + wn * 2 + 0) * 65536 + 1 * 1024 + lane * 16;
    const signed char* pb3 = Wq + (long)(bn * 8 + wn * 2 + 1) * 65536 + 1 * 1024 + lane * 16;
#define LDB(p, off) (*(const i32x4*)((p) + (off)))

    // A read base: wave half within slot
    const signed char* Aw = lds + wm * 8192 + lane * 16;

    f32x16 acc[4][2];
#pragma unroll
    for (int i = 0; i < 4; ++i)
#pragma unroll
        for (int j = 0; j < 2; ++j)
            acc[i][j] = (f32x16){0.f};

    // 16 MFMA + 8 A ds_reads; B operands from registers
#define BODY(slot, B0, B1, B2, B3) do {                                        \
    const signed char* A = Aw + (slot) * 16384;                                \
    i32x4 a00 = *(const i32x4*)(A + 0 * 1024);                                 \
    i32x4 a10 = *(const i32x4*)(A + 2 * 1024);                                 \
    acc[0][0] = MFMA32(a00, B0, acc[0][0]);                                    \
    acc[0][1] = MFMA32(a00, B1, acc[0][1]);                                    \
    acc[1][0] = MFMA32(a10, B0, acc[1][0]);                                    \
    acc[1][1] = MFMA32(a10, B1, acc[1][1]);                                    \
    i32x4 a20 = *(const i32x4*)(A + 4 * 1024);                                 \
    i32x4 a30 = *(const i32x4*)(A + 6 * 1024);                                 \
    acc[2][0] = MFMA32(a20, B0, acc[2][0]);                                    \
    acc[2][1] = MFMA32(a20, B1, acc[2][1]);                                    \
    acc[3][0] = MFMA32(a30, B0, acc[3][0]);                                    \
    acc[3][1] = MFMA32(a30, B1, acc[3][1]);                                    \
    i32x4 a01 = *(const i32x4*)(A + 1 * 1024);                                 \
    i32x4 a11 = *(const i32x4*)(A + 3 * 1024);                                 \
    acc[0][0] = MFMA32(a01, B2, acc[0][0]);                                    \
    acc[0][1] = MFMA32(a01, B3, acc[0][1]);                                    \
    acc[1][0] = MFMA32(a11, B2, acc[1][0]);                                    \
    acc[1][1] = MFMA32(a11, B3, acc[1][1]);                                    \
    i32x4 a21 = *(const i32x4*)(A + 5 * 1024);                                 \
    i32x4 a31 = *(const i32x4*)(A + 7 * 1024);                                 \
    acc[2][0] = MFMA32(a21, B2, acc[2][0]);                                    \
    acc[2][1] = MFMA32(a21, B3, acc[2][1]);                                    \
    acc[3][0] = MFMA32(a31, B2, acc[3][0]);                                    \
    acc[3][1] = MFMA32(a31, B3, acc[3][1]);                                    \
} while (0)

    // prologue: tile 0 -> slot 0 (A) + even B buffer. 6 VMEM ops in flight.
    STAGE_A(0, 0);
    i32x4 e0 = LDB(pb0, 0), e1 = LDB(pb1, 0), e2 = LDB(pb2, 0), e3 = LDB(pb3, 0);
    i32x4 o0, o1, o2, o3;

    for (int d = 0; d < 16; ++d) {
        int g0 = 2 * d;
        // ---- even tile g0 (slot 0, B regs e*) ----
        __builtin_amdgcn_s_barrier();              // slot 1 free (tile g0-1 done)
        {
            STAGE_A(1, g0 + 1);
            long kn = (long)(g0 + 1) * 2048;
            o0 = LDB(pb0, kn); o1 = LDB(pb1, kn); o2 = LDB(pb2, kn); o3 = LDB(pb3, kn);
            asm volatile("s_waitcnt vmcnt(6)" ::: "memory");   // tile g0 A+B landed
        }
        __builtin_amdgcn_s_barrier();              // publish slot-0 A to all waves
        __builtin_amdgcn_sched_barrier(0);
        __builtin_amdgcn_s_setprio(1);
        BODY(0, e0, e1, e2, e3);
        __builtin_amdgcn_s_setprio(0);
        // ---- odd tile g0+1 (slot 1, B regs o*) ----
        __builtin_amdgcn_s_barrier();              // slot 0 free
        if (d < 15) {
            STAGE_A(0, g0 + 2);
            long kn = (long)(g0 + 2) * 2048;
            e0 = LDB(pb0, kn); e1 = LDB(pb1, kn); e2 = LDB(pb2, kn); e3 = LDB(pb3, kn);
            asm volatile("s_waitcnt vmcnt(6)" ::: "memory");
        } else {
            asm volatile("s_waitcnt vmcnt(0)" ::: "memory");   // final drain
        }
        __builtin_amdgcn_s_barrier();              // publish slot-1 A
        __builtin_amdgcn_sched_barrier(0);
        __builtin_amdgcn_s_setprio(1);
        BODY(1, o0, o1, o2, o3);
        __builtin_amdgcn_s_setprio(0);
    }

    // epilogue: 32x32 C/D mapping: col = lane&31, row = (r&3) + 8*(r>>2) + 4*(lane>>5)
#pragma unroll
    for (int mi = 0; mi < 4; ++mi) {
#pragma unroll
        for (int ni = 0; ni < 2; ++ni) {
            long col = col0 + wn * 64 + ni * 32 + (lane & 31);
            long rowb = row0 + wm * 128 + mi * 32 + 4 * (lane >> 5);
#pragma unroll
            for (int r = 0; r < 16; ++r) {
                long row = rowb + (r & 3) + 8 * (r >> 2);
                out[row * NCOLS + col] = alpha * acc[mi][ni][r];
            }
        }
    }
#undef BODY
#undef LDB
#undef STAGE_A
}

// ---------------- host launch ----------------------------------------------------
extern "C" void kernel_launch(void* const* d_in, const int* in_sizes, int n_in,
                              void* d_out, int out_size, void* d_ws, size_t ws_size,
                              hipStream_t stream) {
    const float* x = (const float*)d_in[0];   // 8192 x 4096 f32
    const float* w = (const float*)d_in[1];   // 4096 x 4096 f32
    float* out = (float*)d_out;               // 8192 x 4096 f32

    uint8_t* ws = (uint8_t*)d_ws;
    signed char* Xq = (signed char*)ws;                  // fp4 ternary x, permuted (16 MB)
    signed char* Wq = (signed char*)(ws + XQ_BYTES);     // fp4 ternary w, permuted (8 MB)
    float* scal = (float*)(ws + SCAL_OFF);               // [delta_x, delta_w, alpha, pad]
    // partials at scal+4 (768 floats)

    k_reduce_abs<<<768, 256, 0, stream>>>(x, w, scal + 4);
    k_finalize<<<1, 256, 0, stream>>>(scal);
    k_quantF<<<6144, 256, 0, stream>>>(x, w, (uint4*)Xq, (uint4*)Wq, scal);
    k_gemm<<<512, 512, 0, stream>>>(Xq, Wq, out, scal);
}

// Round 12
// 154.218 us; speedup vs baseline: 1.0699x; 1.0699x over previous
//
#include <hip/hip_runtime.h>
#include <stdint.h>

typedef __attribute__((ext_vector_type(4))) int i32x4;
typedef __attribute__((ext_vector_type(16))) float f32x16;

#define MROWS 8192L
#define NCOLS 4096L
#define KDIM  4096L

#define XQ_BYTES   (MROWS * KDIM / 2)            // 16777216 (fp4, fragment-permuted)
#define WQ_BYTES   (NCOLS * KDIM / 2)            // 8388608
#define SCAL_OFF   (XQ_BYTES + WQ_BYTES)

// ---------------- reduction: sum|x| (blocks 0..511), sum|w| (blocks 512..767) ----
__global__ __launch_bounds__(256) void k_reduce_abs(const float* __restrict__ x,
                                                    const float* __restrict__ w,
                                                    float* __restrict__ partials) {
    __shared__ float sm[256];
    int b = blockIdx.x;
    int t = threadIdx.x;
    const float4* v;
    long base;
    if (b < 512) { v = (const float4*)x; base = (long)b * 16384; }
    else         { v = (const float4*)w; base = (long)(b - 512) * 16384; }
    float s = 0.f;
    for (int i = t; i < 16384; i += 256) {
        float4 q = v[base + i];
        s += fabsf(q.x) + fabsf(q.y) + fabsf(q.z) + fabsf(q.w);
    }
    sm[t] = s;
    __syncthreads();
    for (int off = 128; off > 0; off >>= 1) {
        if (t < off) sm[t] += sm[t + off];
        __syncthreads();
    }
    if (t == 0) partials[b] = sm[0];
}

// ---------------- finalize: double-precision combine, write scalars --------------
__global__ __launch_bounds__(256) void k_finalize(float* __restrict__ scal) {
    const float* partials = scal + 4;
    __shared__ double sm[256];
    int t = threadIdx.x;

    double sx = 0.0;
    for (int i = t; i < 512; i += 256) sx += (double)partials[i];
    sm[t] = sx;
    __syncthreads();
    for (int off = 128; off > 0; off >>= 1) {
        if (t < off) sm[t] += sm[t + off];
        __syncthreads();
    }
    double SX = sm[0];
    __syncthreads();

    double sw = (double)partials[512 + t];
    sm[t] = sw;
    __syncthreads();
    for (int off = 128; off > 0; off >>= 1) {
        if (t < off) sm[t] += sm[t + off];
        __syncthreads();
    }
    if (t == 0) {
        float meanx = (float)(SX / 33554432.0);
        float meanw = (float)(sm[0] / 16777216.0);
        scal[0] = 0.1f * meanx;   // delta_x
        scal[1] = 0.05f * meanw;  // delta_w
        scal[2] = meanw;          // alpha
    }
}

// ---------------- ternarize to fp4 e2m1 {-1,0,1}, fragment-permuted output -------
// Layout (X): 1KB block BX = (rowblk*32 + ktile)*2 + ks ; inside: [khalf(2)][r32(32)][16B]
__device__ __forceinline__ unsigned int nib4(float v, float delta) {
    return v > delta ? 2u : (v < -delta ? 10u : 0u);   // +1=0x2, -1=0xA, 0=0x0
}

__global__ __launch_bounds__(256) void k_quantF(const float* __restrict__ x,
                                                const float* __restrict__ w,
                                                uint4* __restrict__ xq,
                                                uint4* __restrict__ wq,
                                                const float* __restrict__ scal) {
    int wv = blockIdx.x * 4 + (threadIdx.x >> 6);   // wave task id, 0..24575
    int l = threadIdx.x & 63;

    const float* src;
    uint4* dst;
    float delta;
    int task;                        // block index within its tensor
    if (wv < 16384) {                // X: rowblk(256) x ktile(32) x ks(2)
        src = x; dst = xq; delta = scal[0]; task = wv;
    } else {                         // W: colblk(128) x ktile(32) x ks(2)
        src = w; dst = wq; delta = scal[1]; task = wv - 16384;
    }
    int rowblk = task >> 6;
    int rest = task & 63;            // ktile*2 + ks
    long row = (long)rowblk * 32 + (l & 31);
    long fidx = row * 4096 + (long)(rest >> 1) * 128 + (long)(rest & 1) * 64
              + (long)(l >> 5) * 32;
    const float4* s4 = (const float4*)(src + fidx);

    unsigned int ow[4];
#pragma unroll
    for (int c = 0; c < 4; ++c) {
        float4 q0 = s4[2 * c];
        float4 q1 = s4[2 * c + 1];
        ow[c] = nib4(q0.x, delta)
              | (nib4(q0.y, delta) << 4)
              | (nib4(q0.z, delta) << 8)
              | (nib4(q0.w, delta) << 12)
              | (nib4(q1.x, delta) << 16)
              | (nib4(q1.y, delta) << 20)
              | (nib4(q1.z, delta) << 24)
              | (nib4(q1.w, delta) << 28);
    }
    uint4 o; o.x = ow[0]; o.y = ow[1]; o.z = ow[2]; o.w = ow[3];
    dst[(long)task * 64 + l] = o;    // 64 lanes x 16B = contiguous 1KB
}

// ---- GEMM common: fp4 32x32x64, fragment-major LDS, 4-slot ring -----------------
#define GLOAD_LDS16(g, l)                                                             \
    __builtin_amdgcn_global_load_lds((const __attribute__((address_space(1))) void*)(g), \
                                     (__attribute__((address_space(3))) void*)(l),       \
                                     16, 0, 0)

#define MK8(v) __builtin_shufflevector((v), (v), 0, 1, 2, 3, -1, -1, -1, -1)

#define MFMA32(a, b, c)                                                       \
    __builtin_amdgcn_mfma_scale_f32_32x32x64_f8f6f4(MK8(a), MK8(b), (c),      \
        4, 4, 0, 0x7F7F7F7F, 0, 0x7F7F7F7F)

// common prologue: index math + stage pointers (256 blocks, half-M grid)
#define GEMM_SETUP()                                                           \
    const float alpha = scal[2];                                               \
    int bid = (int)blockIdx.x;                                                 \
    bid = (bid & 7) * 32 + (bid >> 3);          /* 256 % 8 == 0, bijective */  \
    int bm = bm_base + (bid >> 4);              /* 16 M-tiles per half */      \
    int bn = bid & 15;                                                         \
    long row0 = (long)bm * 256;                                                \
    long col0 = (long)bn * 256;                                                \
    int t = threadIdx.x;                                                       \
    int lane = t & 63;                                                         \
    int wid = t >> 6;                                                          \
    int wm = wid >> 2;                                                         \
    int wn = wid & 3;                                                          \
    const signed char* sp[4];                                                  \
    int ldoff[4];                                                              \
    _Pragma("unroll")                                                          \
    for (int j = 0; j < 4; ++j) {                                              \
        int g = wid * 4 + j;                                                   \
        ldoff[j] = g * 1024;                                                   \
        if (g < 16) {                                                          \
            long rowblk = bm * 8 + (g >> 3) * 4 + ((g >> 1) & 3);              \
            sp[j] = Xq + rowblk * 65536 + (g & 1) * 1024 + lane * 16;          \
        } else {                                                               \
            int h = g - 16;                                                    \
            long colblk = bn * 8 + (h >> 2) * 2 + ((h >> 1) & 1);              \
            sp[j] = Wq + colblk * 65536 + (h & 1) * 1024 + lane * 16;          \
        }                                                                      \
    }                                                                          \
    const signed char* Ab = lds + wm * 8192 + lane * 16;                       \
    const signed char* Bb = lds + 16384 + wn * 4096 + lane * 16;               \
    f32x16 acc[4][2];                                                          \
    _Pragma("unroll")                                                          \
    for (int i = 0; i < 4; ++i)                                                \
        _Pragma("unroll")                                                      \
        for (int j = 0; j < 2; ++j)                                            \
            acc[i][j] = (f32x16){0.f};

#define GEMM_EPILOGUE()                                                        \
    _Pragma("unroll")                                                          \
    for (int mi = 0; mi < 4; ++mi) {                                           \
        _Pragma("unroll")                                                      \
        for (int ni = 0; ni < 2; ++ni) {                                       \
            long col = col0 + wn * 64 + ni * 32 + (lane & 31);                 \
            long rowb = row0 + wm * 128 + mi * 32 + 4 * (lane >> 5);           \
            _Pragma("unroll")                                                  \
            for (int r = 0; r < 16; ++r) {                                     \
                long row = rowb + (r & 3) + 8 * (r >> 2);                      \
                out[row * NCOLS + col] = alpha * acc[mi][ni][r];               \
            }                                                                  \
        }                                                                      \
    }

#define STAGE4(slot, g1) do {                                                  \
    signed char* sb_ = lds + (slot) * 32768;                                   \
    _Pragma("unroll")                                                          \
    for (int j_ = 0; j_ < 4; ++j_)                                             \
        GLOAD_LDS16(sp[j_] + (long)(g1) * 2048, sb_ + ldoff[j_]);              \
} while (0)

// ================= VARIANT A: R8 double-group (control) ==========================
__global__ __launch_bounds__(512, 2) void k_gemmA(const signed char* __restrict__ Xq,
                                                  const signed char* __restrict__ Wq,
                                                  float* __restrict__ out,
                                                  const float* __restrict__ scal,
                                                  int bm_base) {
    __shared__ __attribute__((aligned(16))) signed char lds[131072];
    GEMM_SETUP();

#define BODYA(slot) do {                                                       \
    const signed char* A = Ab + (slot) * 32768;                                \
    const signed char* B = Bb + (slot) * 32768;                                \
    i32x4 b00 = *(const i32x4*)(B + 0 * 1024);                                 \
    i32x4 b10 = *(const i32x4*)(B + 2 * 1024);                                 \
    i32x4 a00 = *(const i32x4*)(A + 0 * 1024);                                 \
    i32x4 a10 = *(const i32x4*)(A + 2 * 1024);                                 \
    acc[0][0] = MFMA32(a00, b00, acc[0][0]);                                   \
    acc[1][0] = MFMA32(a10, b00, acc[1][0]);                                   \
    acc[0][1] = MFMA32(a00, b10, acc[0][1]);                                   \
    acc[1][1] = MFMA32(a10, b10, acc[1][1]);                                   \
    i32x4 b01 = *(const i32x4*)(B + 1 * 1024);                                 \
    i32x4 b11 = *(const i32x4*)(B + 3 * 1024);                                 \
    i32x4 a01 = *(const i32x4*)(A + 1 * 1024);                                 \
    i32x4 a11 = *(const i32x4*)(A + 3 * 1024);                                 \
    acc[0][0] = MFMA32(a01, b01, acc[0][0]);                                   \
    acc[1][0] = MFMA32(a11, b01, acc[1][0]);                                   \
    acc[0][1] = MFMA32(a01, b11, acc[0][1]);                                   \
    acc[1][1] = MFMA32(a11, b11, acc[1][1]);                                   \
    i32x4 a20 = *(const i32x4*)(A + 4 * 1024);                                 \
    i32x4 a30 = *(const i32x4*)(A + 6 * 1024);                                 \
    acc[2][0] = MFMA32(a20, b00, acc[2][0]);                                   \
    acc[3][0] = MFMA32(a30, b00, acc[3][0]);                                   \
    acc[2][1] = MFMA32(a20, b10, acc[2][1]);                                   \
    acc[3][1] = MFMA32(a30, b10, acc[3][1]);                                   \
    i32x4 a21 = *(const i32x4*)(A + 5 * 1024);                                 \
    i32x4 a31 = *(const i32x4*)(A + 7 * 1024);                                 \
    acc[2][0] = MFMA32(a21, b01, acc[2][0]);                                   \
    acc[3][0] = MFMA32(a31, b01, acc[3][0]);                                   \
    acc[2][1] = MFMA32(a21, b11, acc[2][1]);                                   \
    acc[3][1] = MFMA32(a31, b11, acc[3][1]);                                   \
} while (0)

    STAGE4(0, 0);
    STAGE4(1, 1);

    for (int d = 0; d < 16; ++d) {
        int s0 = (2 * d) & 3;
        int s1 = (2 * d + 1) & 3;
        __builtin_amdgcn_s_barrier();
        if (d < 15) {
            STAGE4((2 * d + 2) & 3, 2 * d + 2);
            STAGE4((2 * d + 3) & 3, 2 * d + 3);
            asm volatile("s_waitcnt vmcnt(8)" ::: "memory");
        } else {
            asm volatile("s_waitcnt vmcnt(0)" ::: "memory");
        }
        __builtin_amdgcn_s_barrier();
        __builtin_amdgcn_sched_barrier(0);
        __builtin_amdgcn_s_setprio(1);
        BODYA(s0);
        BODYA(s1);
        __builtin_amdgcn_s_setprio(0);
    }
    GEMM_EPILOGUE();
#undef BODYA
}

// ================= VARIANT B: m201-style 8-phase fabric ==========================
#define PH_PRE() do {                                        \
    __builtin_amdgcn_s_barrier();                            \
    asm volatile("s_waitcnt lgkmcnt(0)" ::: "memory");       \
    __builtin_amdgcn_sched_barrier(0);                       \
    __builtin_amdgcn_s_setprio(1); } while (0)
#define PH_POST() do {                                       \
    __builtin_amdgcn_s_setprio(0);                           \
    __builtin_amdgcn_s_barrier(); } while (0)
#define PH_POST_V() do {                                     \
    __builtin_amdgcn_s_setprio(0);                           \
    asm volatile("s_waitcnt vmcnt(4)" ::: "memory");         \
    __builtin_amdgcn_s_barrier(); } while (0)

__global__ __launch_bounds__(512, 2) void k_gemmB(const signed char* __restrict__ Xq,
                                                  const signed char* __restrict__ Wq,
                                                  float* __restrict__ out,
                                                  const float* __restrict__ scal,
                                                  int bm_base) {
    __shared__ __attribute__((aligned(16))) signed char lds[131072];
    GEMM_SETUP();

    // prologue: tiles 0,1 -> slots 0,1; certify tile 0 (tile 1 stays in flight)
    STAGE4(0, 0);
    STAGE4(1, 1);
    asm volatile("s_waitcnt vmcnt(4)" ::: "memory");
    __builtin_amdgcn_s_barrier();

    for (int d = 0; d < 16; ++d) {
        int s0 = (2 * d) & 3;
        int s1 = (2 * d + 1) & 3;
        int tg0 = (2 * d + 2) & 31;        // stage target K-tiles (wrap: harmless)
        int tg1 = (2 * d + 3) & 31;
        int sl0 = (2 * d + 2) & 3;
        int sl1 = (2 * d + 3) & 3;
        signed char* sb0 = lds + sl0 * 32768;
        signed char* sb1 = lds + sl1 * 32768;

        const signed char* A = Ab + s0 * 32768;
        const signed char* B = Bb + s0 * 32768;
        i32x4 a00, a10, a20, a30, a01, a11, a21, a31, b00, b10, b01, b11;

        // ---- tile s0: phases 1-4 ----
        b00 = *(const i32x4*)(B + 0 * 1024);
        b10 = *(const i32x4*)(B + 2 * 1024);
        a00 = *(const i32x4*)(A + 0 * 1024);
        a10 = *(const i32x4*)(A + 2 * 1024);
        GLOAD_LDS16(sp[0] + (long)tg0 * 2048, sb0 + ldoff[0]);
        PH_PRE();
        acc[0][0] = MFMA32(a00, b00, acc[0][0]);
        acc[1][0] = MFMA32(a10, b00, acc[1][0]);
        acc[0][1] = MFMA32(a00, b10, acc[0][1]);
        acc[1][1] = MFMA32(a10, b10, acc[1][1]);
        PH_POST();

        b01 = *(const i32x4*)(B + 1 * 1024);
        b11 = *(const i32x4*)(B + 3 * 1024);
        a01 = *(const i32x4*)(A + 1 * 1024);
        a11 = *(const i32x4*)(A + 3 * 1024);
        GLOAD_LDS16(sp[1] + (long)tg0 * 2048, sb0 + ldoff[1]);
        PH_PRE();
        acc[0][0] = MFMA32(a01, b01, acc[0][0]);
        acc[1][0] = MFMA32(a11, b01, acc[1][0]);
        acc[0][1] = MFMA32(a01, b11, acc[0][1]);
        acc[1][1] = MFMA32(a11, b11, acc[1][1]);
        PH_POST();

        a20 = *(const i32x4*)(A + 4 * 1024);
        a30 = *(const i32x4*)(A + 6 * 1024);
        GLOAD_LDS16(sp[2] + (long)tg0 * 2048, sb0 + ldoff[2]);
        PH_PRE();
        acc[2][0] = MFMA32(a20, b00, acc[2][0]);
        acc[3][0] = MFMA32(a30, b00, acc[3][0]);
        acc[2][1] = MFMA32(a20, b10, acc[2][1]);
        acc[3][1] = MFMA32(a30, b10, acc[3][1]);
        PH_POST();

        a21 = *(const i32x4*)(A + 5 * 1024);
        a31 = *(const i32x4*)(A + 7 * 1024);
        GLOAD_LDS16(sp[3] + (long)tg0 * 2048, sb0 + ldoff[3]);
        PH_PRE();
        acc[2][0] = MFMA32(a21, b01, acc[2][0]);
        acc[3][0] = MFMA32(a31, b01, acc[3][0]);
        acc[2][1] = MFMA32(a21, b11, acc[2][1]);
        acc[3][1] = MFMA32(a31, b11, acc[3][1]);
        PH_POST_V();                      // certify tile s1 (retire its 4 loads)

        // ---- tile s1: phases 5-8 ----
        A = Ab + s1 * 32768;
        B = Bb + s1 * 32768;

        b00 = *(const i32x4*)(B + 0 * 1024);
        b10 = *(const i32x4*)(B + 2 * 1024);
        a00 = *(const i32x4*)(A + 0 * 1024);
        a10 = *(const i32x4*)(A + 2 * 1024);
        GLOAD_LDS16(sp[0] + (long)tg1 * 2048, sb1 + ldoff[0]);
        PH_PRE();
        acc[0][0] = MFMA32(a00, b00, acc[0][0]);
        acc[1][0] = MFMA32(a10, b00, acc[1][0]);
        acc[0][1] = MFMA32(a00, b10, acc[0][1]);
        acc[1][1] = MFMA32(a10, b10, acc[1][1]);
        PH_POST();

        b01 = *(const i32x4*)(B + 1 * 1024);
        b11 = *(const i32x4*)(B + 3 * 1024);
        a01 = *(const i32x4*)(A + 1 * 1024);
        a11 = *(const i32x4*)(A + 3 * 1024);
        GLOAD_LDS16(sp[1] + (long)tg1 * 2048, sb1 + ldoff[1]);
        PH_PRE();
        acc[0][0] = MFMA32(a01, b01, acc[0][0]);
        acc[1][0] = MFMA32(a11, b01, acc[1][0]);
        acc[0][1] = MFMA32(a01, b11, acc[0][1]);
        acc[1][1] = MFMA32(a11, b11, acc[1][1]);
        PH_POST();

        a20 = *(const i32x4*)(A + 4 * 1024);
        a30 = *(const i32x4*)(A + 6 * 1024);
        GLOAD_LDS16(sp[2] + (long)tg1 * 2048, sb1 + ldoff[2]);
        PH_PRE();
        acc[2][0] = MFMA32(a20, b00, acc[2][0]);
        acc[3][0] = MFMA32(a30, b00, acc[3][0]);
        acc[2][1] = MFMA32(a20, b10, acc[2][1]);
        acc[3][1] = MFMA32(a30, b10, acc[3][1]);
        PH_POST();

        a21 = *(const i32x4*)(A + 5 * 1024);
        a31 = *(const i32x4*)(A + 7 * 1024);
        GLOAD_LDS16(sp[3] + (long)tg1 * 2048, sb1 + ldoff[3]);
        PH_PRE();
        acc[2][0] = MFMA32(a21, b01, acc[2][0]);
        acc[3][0] = MFMA32(a31, b01, acc[3][0]);
        acc[2][1] = MFMA32(a21, b11, acc[2][1]);
        acc[3][1] = MFMA32(a31, b11, acc[3][1]);
        PH_POST_V();                      // certify next tile s0 (tiles wrap at end)
    }
    GEMM_EPILOGUE();
}

// ---------------- host launch ----------------------------------------------------
extern "C" void kernel_launch(void* const* d_in, const int* in_sizes, int n_in,
                              void* d_out, int out_size, void* d_ws, size_t ws_size,
                              hipStream_t stream) {
    const float* x = (const float*)d_in[0];   // 8192 x 4096 f32
    const float* w = (const float*)d_in[1];   // 4096 x 4096 f32
    float* out = (float*)d_out;               // 8192 x 4096 f32

    uint8_t* ws = (uint8_t*)d_ws;
    signed char* Xq = (signed char*)ws;                  // fp4 ternary x, permuted (16 MB)
    signed char* Wq = (signed char*)(ws + XQ_BYTES);     // fp4 ternary w, permuted (8 MB)
    float* scal = (float*)(ws + SCAL_OFF);               // [delta_x, delta_w, alpha, pad]
    // partials at scal+4 (768 floats)

    k_reduce_abs<<<768, 256, 0, stream>>>(x, w, scal + 4);
    k_finalize<<<1, 256, 0, stream>>>(scal);
    k_quantF<<<6144, 256, 0, stream>>>(x, w, (uint4*)Xq, (uint4*)Wq, scal);
    // A/B: rows 0-4095 via R8-control, rows 4096-8191 via 8-phase variant
    k_gemmA<<<256, 512, 0, stream>>>(Xq, Wq, out, scal, 0);
    k_gemmB<<<256, 512, 0, stream>>>(Xq, Wq, out, scal, 16);
}